// Round 7
// baseline (185.403 us; speedup 1.0000x reference)
//
#include <hip/hip_runtime.h>
#include <cstdint>
#include <cstddef>

#define S_LEN 2047
#define BATCH 8
#define R_TOT 1162
#define NCHUNK 8
#define NEGV (-1e9f)

// ws layout: local  = 8*2047*6*4 = 393,024 B @ 0
//            carry  = 8*8*6*4    =   1,536 B @ 393,024
//            params = 16376*18*4 = 1,179,072 B @ 394,560  (ends 1,573,632 —
//            inside the round-5-proven 1,703,104 B workspace bound)
#define CARRY_OFF 393024
#define PARAM_OFF 394560
#define PSTRIDE 18

__device__ __constant__ int d_numerators[12] = {1, 2, 3, 4, 5, 6, 7, 8, 9, 10, 12, 16};

// ---------------------------------------------------------------------------
// Kernel 1: within-chunk inclusive scan — VERBATIM round-6 (passing).
// ---------------------------------------------------------------------------
__global__ __launch_bounds__(256) void scan_local(const int* __restrict__ song,
                                                  unsigned* __restrict__ local) {
    const int b = blockIdx.x >> 3;
    const int c = blockIdx.x & 7;
    const int tid = threadIdx.x;
    const int j = c * 256 + tid;
    __shared__ unsigned lds_f[3][256];
    __shared__ unsigned lds_inst[5][256];
    const unsigned HAS = 1u << 16;
    const long base = (long)b * S_LEN;

    unsigned e_f[3] = {0, 0, 0};
    unsigned e_inst[5] = {0, 0, 0, 0, 0};
    if (j < S_LEN) {
        const int* rj = song + (base + j) * 11;
        const int type = rj[0];
        if (type == 4)      e_f[0] = HAS | (unsigned)rj[8];
        else if (type == 5) e_f[1] = HAS | (unsigned)rj[9];
        else if (type == 6) e_f[2] = HAS | (unsigned)rj[10];
        else if (type == 1) { const int v = rj[6]; e_inst[v >> 5] = 1u << (v & 31); }
    }
#pragma unroll
    for (int w = 0; w < 3; w++) lds_f[w][tid] = e_f[w];
#pragma unroll
    for (int w = 0; w < 5; w++) lds_inst[w][tid] = e_inst[w];
    __syncthreads();

    for (int off = 1; off < 256; off <<= 1) {
        unsigned p_f[3] = {0, 0, 0};
        unsigned p_inst[5] = {0, 0, 0, 0, 0};
        if (tid >= off) {
#pragma unroll
            for (int w = 0; w < 3; w++) p_f[w] = lds_f[w][tid - off];
#pragma unroll
            for (int w = 0; w < 5; w++) p_inst[w] = lds_inst[w][tid - off];
        }
        __syncthreads();
        if (tid >= off) {
#pragma unroll
            for (int w = 0; w < 3; w++) {
                if (!(e_f[w] & HAS)) e_f[w] = p_f[w];
                lds_f[w][tid] = e_f[w];
            }
#pragma unroll
            for (int w = 0; w < 5; w++) {
                e_inst[w] |= p_inst[w];
                lds_inst[w][tid] = e_inst[w];
            }
        }
        __syncthreads();
    }

    if (j < S_LEN) {
        const unsigned w0 =
            (e_f[0] & 0xFFu) | ((e_f[1] & 0xFFu) << 8) | ((e_f[2] & 0xFFu) << 16) |
            (((e_f[0] >> 16) & 1u) << 24) | (((e_f[1] >> 16) & 1u) << 25) |
            (((e_f[2] >> 16) & 1u) << 26);
        unsigned* sp = local + (size_t)(base + j) * 6;
        sp[0] = w0;
#pragma unroll
        for (int w = 0; w < 5; w++) sp[1 + w] = e_inst[w];
    }
}

// ---------------------------------------------------------------------------
// Kernel 2: exclusive per-chunk carries — VERBATIM round-6 (passing).
// ---------------------------------------------------------------------------
__global__ __launch_bounds__(64) void scan_carry(const int* __restrict__ song,
                                                 const unsigned* __restrict__ local,
                                                 unsigned* __restrict__ carry) {
    const int b = threadIdx.x;
    if (b >= BATCH) return;
    const int* r0 = song + (size_t)b * S_LEN * 11;
    unsigned cks = (unsigned)r0[8], cts = (unsigned)r0[9], ctp = (unsigned)r0[10];
    unsigned chas = 0;
    unsigned cinst[5] = {0, 0, 0, 0, 0};
    for (int c = 0; c < NCHUNK; c++) {
        unsigned* cp = carry + ((size_t)b * NCHUNK + c) * 6;
        cp[0] = (cks & 0xFFu) | ((cts & 0xFFu) << 8) | ((ctp & 0xFFu) << 16) | (chas << 24);
#pragma unroll
        for (int w = 0; w < 5; w++) cp[1 + w] = cinst[w];
        const int pos = min((c + 1) * 256, S_LEN) - 1;
        const unsigned* lp = local + ((size_t)b * S_LEN + pos) * 6;
        const unsigned a0 = lp[0];
        if ((a0 >> 24) & 1u) cks = a0 & 0xFFu;
        if ((a0 >> 25) & 1u) cts = (a0 >> 8) & 0xFFu;
        if ((a0 >> 26) & 1u) ctp = (a0 >> 16) & 0xFFu;
        chas |= (a0 >> 24) & 7u;
#pragma unroll
        for (int w = 0; w < 5; w++) cinst[w] |= lp[1 + w];
    }
}

// ---------------------------------------------------------------------------
// Kernel 3: per-row parameter computation — round-5-proven head (LDS tree
// argmax + thread-0 epilogue) with the round-6-proven local+carry combine in
// the state-load branch. Writes 17 params per row, stride PSTRIDE.
// ---------------------------------------------------------------------------
__global__ __launch_bounds__(256) void param_kernel(const int* __restrict__ song,
                                                    const int* __restrict__ ctype,
                                                    const float* __restrict__ scores,
                                                    const unsigned* __restrict__ local,
                                                    const unsigned* __restrict__ carry,
                                                    int* __restrict__ params) {
    const int row = blockIdx.x;
    const int tid = threadIdx.x;
    const int b = row / S_LEN;
    const int i = row - b * S_LEN;

    __shared__ float s_val[128];
    __shared__ int   s_idx[128];
    __shared__ float sb_val[8];
    __shared__ int   sb_idx[8];
    __shared__ int   s_info[10];

    const size_t rbase = (size_t)row * R_TOT;
    const float2* s2 = (const float2*)(scores + rbase);

    const float2 r0 = s2[tid];

    if (tid < 128) {
        const bool sec = (r0.y > r0.x);
        s_val[tid] = sec ? r0.y : r0.x;
        s_idx[tid] = 2 * tid + (sec ? 1 : 0);
    } else if (tid < 136) {
        const bool sec = (r0.y > r0.x);
        sb_val[tid - 128] = sec ? r0.y : r0.x;
        sb_idx[tid - 128] = (2 * tid - 256) + (sec ? 1 : 0);
    } else if (tid < 142) {
        const int w = tid - 136;
        const int e = min(i + 1, S_LEN - 1);
        const unsigned lw = local[((size_t)b * S_LEN + e) * 6 + w];
        const unsigned cw = carry[((size_t)b * NCHUNK + (e >> 8)) * 6 + w];
        unsigned v;
        if (w == 0) {
            const unsigned ks = ((lw >> 24) & 1u) ? (lw & 0xFFu) : (cw & 0xFFu);
            const unsigned ts = ((lw >> 25) & 1u) ? ((lw >> 8) & 0xFFu) : ((cw >> 8) & 0xFFu);
            const unsigned tp = ((lw >> 26) & 1u) ? ((lw >> 16) & 0xFFu) : ((cw >> 16) & 0xFFu);
            const unsigned hks = ((lw >> 24) | (cw >> 24)) & 1u;
            const unsigned hts = ((lw >> 25) | (cw >> 25)) & 1u;
            v = ks | (ts << 8) | (tp << 16) | (hks << 24) | (hts << 25);
        } else {
            v = lw | cw;
        }
        s_info[w] = (int)v;
    } else if (tid < 146) {
        const int* srow = song + (size_t)row * 11;
        if (tid == 142) s_info[6] = srow[1];
        if (tid == 143) s_info[7] = srow[2];
        if (tid == 144) s_info[8] = srow[3];
        if (tid == 145) s_info[9] = ctype[row];
    }
    __syncthreads();

    for (int s = 64; s > 0; s >>= 1) {
        if (tid < s) {
            if (s_val[tid + s] > s_val[tid]) {  // strict > keeps lower index on tie
                s_val[tid] = s_val[tid + s];
                s_idx[tid] = s_idx[tid + s];
            }
        }
        __syncthreads();
    }

    if (tid == 0) {
        const int pred_m = s_idx[0];
        float bv = sb_val[0];
        int pred_b = sb_idx[0];
#pragma unroll
        for (int q = 1; q < 8; q++) {
            if (sb_val[q] > bv) { bv = sb_val[q]; pred_b = sb_idx[q]; }
        }
        const unsigned pack = (unsigned)s_info[0];
        const int song1 = s_info[6], song2 = s_info[7], song3 = s_info[8];
        const int t = s_info[9];
        const bool c1 = (pred_m == song1);
        const int min_beat = c1 ? song2 : 0;
        const bool c2 = c1 && (pred_b == min_beat);
        const int min_pos = c2 ? song3 : 0;
        const int last_ks = (int)(pack & 0xFFu);
        const int last_ts = (int)((pack >> 8) & 0xFFu);
        const int last_tp = (int)((pack >> 16) & 0xFFu);
        const unsigned u = (unsigned)s_info[1] | (unsigned)s_info[2] | (unsigned)s_info[3] |
                           (unsigned)s_info[4] | (unsigned)s_info[5];
        int* pp = params + (size_t)row * PSTRIDE;
        pp[0] = t;
        pp[1] = song1;                                            // min_measure
        pp[2] = min_beat;
        pp[3] = min_pos;
        pp[4] = (song2 == 0 && song3 == 0) ? song1 : song1 + 1;   // min_m46
        pp[5] = d_numerators[last_ts % 12];                       // max_beat
        pp[6] = last_ks;
        pp[7] = last_ts;
        pp[8] = last_tp;
        pp[9]  = (int)((pack >> 24) & 1u);                        // has_ks
        pp[10] = (int)((pack >> 25) & 1u);                        // has_ts
        pp[11] = (u != 0u);                                       // has_inst
        pp[12] = s_info[1]; pp[13] = s_info[2]; pp[14] = s_info[3];
        pp[15] = s_info[4]; pp[16] = s_info[5];
    }
}

// ---------------------------------------------------------------------------
// Mask predicate — logic VERBATIM from the passing kernels, parameterized.
// ---------------------------------------------------------------------------
struct P {
    int t, min_measure, min_beat, min_pos, min_m46, max_beat;
    int last_ks, last_ts, last_tp;
    int has_ks, has_ts, has_inst;
    unsigned inst[5];
};

__device__ __forceinline__ void load_params(const int* __restrict__ pp, P& p) {
    p.t = pp[0]; p.min_measure = pp[1]; p.min_beat = pp[2]; p.min_pos = pp[3];
    p.min_m46 = pp[4]; p.max_beat = pp[5];
    p.last_ks = pp[6]; p.last_ts = pp[7]; p.last_tp = pp[8];
    p.has_ks = pp[9]; p.has_ts = pp[10]; p.has_inst = pp[11];
#pragma unroll
    for (int w = 0; w < 5; w++) p.inst[w] = (unsigned)pp[12 + w];
}

__device__ __forceinline__ bool maskf(const P& p, int col) {
    const bool is3 = (p.t == 3);
    const bool is46 = (p.t >= 4) && (p.t <= 6);
    // Range offsets: measure 0..256, beat 256..272, position 272..400,
    // duration 400..528, pitch 528..784, instrument 784..913,
    // velocity 913..1041, key_sign 1041..1065, time_sign 1065..1113,
    // tempo 1113..1162
    if (col < 256) {
        if (is3) return col >= p.min_measure;
        if (is46) return col >= p.min_m46;
        return true;
    } else if (col < 272) {
        if (!is3) return true;
        const int v = col - 256;
        return (v >= p.min_beat) && (v < p.max_beat);
    } else if (col < 400) {
        return is3 ? ((col - 272) >= p.min_pos) : true;
    } else if (col < 784) {
        return true;  // duration + pitch
    } else if (col < 913) {
        const int v = col - 784;
        const bool pres = ((p.inst[v >> 5] >> (v & 31)) & 1u) != 0u;
        if (is3) return pres;
        if (p.t == 1) return p.has_inst ? !pres : true;
        return true;
    } else if (col < 1041) {
        return true;  // velocity
    } else if (col < 1065) {
        const int v = col - 1041;
        if (is3) return v == p.last_ks;
        if (p.t == 4) return p.has_ks ? (v != p.last_ks) : true;
        return true;
    } else if (col < 1113) {
        const int v = col - 1065;
        if (is3) return v == p.last_ts;
        if (p.t == 5) return p.has_ts ? (v != p.last_ts) : true;
        return true;
    } else {
        const int v = col - 1113;
        if (is3) return v == p.last_tp;
        if (p.t == 6) return v != p.last_tp;  // no has-check for tempo
        return true;
    }
}

// ---------------------------------------------------------------------------
// Kernel 4: mask application — one block per ROW PAIR (2*4648 B = 581 float4,
// 16B-aligned). Zero LDS, zero barriers, float4 loads/stores. Only float4
// index f==290 straddles the row boundary (cols 1160,1161 of A; 0,1 of B).
// ---------------------------------------------------------------------------
__global__ __launch_bounds__(256) void apply2_kernel(const float* __restrict__ scores,
                                                     const int* __restrict__ params,
                                                     float* __restrict__ out) {
    const int pair = blockIdx.x;        // 8188 pairs
    const int tid = threadIdx.x;
    const size_t base = (size_t)pair * (2 * R_TOT);
    const float4* s4 = (const float4*)(scores + base);
    float4* o4 = (float4*)(out + base);

    const float4 r0 = s4[tid];
    const float4 r1 = s4[tid + 256];
    float4 r2 = make_float4(0.f, 0.f, 0.f, 0.f);
    if (tid < 69) r2 = s4[tid + 512];

    P A, B;
    load_params(params + (size_t)(2 * pair) * PSTRIDE, A);
    load_params(params + (size_t)(2 * pair + 1) * PSTRIDE, B);

    // iter 0: f = tid in [0,256) -> cols 4f..4f+3 <= 1027, all row A
    {
        const int c = 4 * tid;
        float4 w;
        w.x = maskf(A, c)     ? r0.x : NEGV;
        w.y = maskf(A, c + 1) ? r0.y : NEGV;
        w.z = maskf(A, c + 2) ? r0.z : NEGV;
        w.w = maskf(A, c + 3) ? r0.w : NEGV;
        o4[tid] = w;
    }
    // iter 1: f = tid+256 in [256,512): f<290 row A, f==290 straddle, f>290 row B
    {
        const int f = tid + 256;
        float4 w;
        if (f < 290) {
            const int c = 4 * f;  // 1024..1159, row A
            w.x = maskf(A, c)     ? r1.x : NEGV;
            w.y = maskf(A, c + 1) ? r1.y : NEGV;
            w.z = maskf(A, c + 2) ? r1.z : NEGV;
            w.w = maskf(A, c + 3) ? r1.w : NEGV;
        } else if (f == 290) {
            w.x = maskf(A, 1160) ? r1.x : NEGV;
            w.y = maskf(A, 1161) ? r1.y : NEGV;
            w.z = maskf(B, 0)    ? r1.z : NEGV;
            w.w = maskf(B, 1)    ? r1.w : NEGV;
        } else {
            const int c = 4 * f - R_TOT;  // 2..1042, row B
            w.x = maskf(B, c)     ? r1.x : NEGV;
            w.y = maskf(B, c + 1) ? r1.y : NEGV;
            w.z = maskf(B, c + 2) ? r1.z : NEGV;
            w.w = maskf(B, c + 3) ? r1.w : NEGV;
        }
        o4[tid + 256] = w;
    }
    // iter 2: f = tid+512 in [512,581) -> cols 886+4*tid..+3, all row B
    if (tid < 69) {
        const int c = 4 * (tid + 512) - R_TOT;  // 886..1158
        float4 w;
        w.x = maskf(B, c)     ? r2.x : NEGV;
        w.y = maskf(B, c + 1) ? r2.y : NEGV;
        w.z = maskf(B, c + 2) ? r2.z : NEGV;
        w.w = maskf(B, c + 3) ? r2.w : NEGV;
        o4[tid + 512] = w;
    }
}

extern "C" void kernel_launch(void* const* d_in, const int* in_sizes, int n_in,
                              void* d_out, int out_size, void* d_ws, size_t ws_size,
                              hipStream_t stream) {
    const int* song = (const int*)d_in[0];
    const int* ctype = (const int*)d_in[1];
    const float* scores = (const float*)d_in[2];
    float* out = (float*)d_out;
    unsigned* local = (unsigned*)d_ws;
    unsigned* carry = (unsigned*)((char*)d_ws + CARRY_OFF);
    int* params = (int*)((char*)d_ws + PARAM_OFF);

    scan_local<<<BATCH * NCHUNK, 256, 0, stream>>>(song, local);
    scan_carry<<<1, 64, 0, stream>>>(song, local, carry);
    param_kernel<<<BATCH * S_LEN, 256, 0, stream>>>(song, ctype, scores, local, carry, params);
    apply2_kernel<<<(BATCH * S_LEN) / 2, 256, 0, stream>>>(scores, params, out);
}